// Round 2
// baseline (8994.822 us; speedup 1.0000x reference)
//
#include <hip/hip_runtime.h>

#define LAYERS 5

__device__ __forceinline__ void atomAddF(float* p, float v) {
    __hip_atomic_fetch_add(p, v, __ATOMIC_RELAXED, __HIP_MEMORY_SCOPE_AGENT);
}

// ---- storage helpers: h can be f32 or bf16(u16) depending on ws_size ----
__device__ __forceinline__ float b2f(unsigned short u) { return __uint_as_float(((unsigned)u) << 16); }
__device__ __forceinline__ unsigned short f2b(float f) {
    unsigned int x = __float_as_uint(f);
    x += 0x7fff + ((x >> 16) & 1);   // round-to-nearest-even
    return (unsigned short)(x >> 16);
}
__device__ __forceinline__ float4 ld4(const float* p) { return *(const float4*)p; }
__device__ __forceinline__ void st4(float* p, float4 v) { *(float4*)p = v; }
__device__ __forceinline__ float4 ld4(const unsigned short* p) {
    ushort4 u = *(const ushort4*)p;
    return make_float4(b2f(u.x), b2f(u.y), b2f(u.z), b2f(u.w));
}
__device__ __forceinline__ void st4(unsigned short* p, float4 v) {
    ushort4 u;
    u.x = f2b(v.x); u.y = f2b(v.y); u.z = f2b(v.z); u.w = f2b(v.w);
    *(ushort4*)p = u;
}

// h[i] = atom_emb[x[i*9]]
template <typename HT>
__global__ void init_h_kernel(const int* __restrict__ x, const float* __restrict__ atom_emb,
                              HT* __restrict__ h, int N) {
    int tid = blockIdx.x * blockDim.x + threadIdx.x;
    if (tid >= N * 32) return;
    int i = tid >> 5;
    int c4 = (tid & 31) << 2;
    int a = x[i * 9];
    float4 v = *(const float4*)(atom_emb + a * 128 + c4);
    st4(h + (size_t)i * 128 + c4, v);
}

// agg[dst] += relu(h[src] + bond_emb[edge_attr[e*3]])
template <typename HT>
__global__ void edge_scatter_kernel(const int* __restrict__ ei, const int* __restrict__ eattr,
                                    const float* __restrict__ bond_emb,
                                    const HT* __restrict__ h, float* __restrict__ agg, int E) {
    __shared__ float bemb[8 * 128];
    for (int i = threadIdx.x; i < 8 * 128; i += blockDim.x) bemb[i] = bond_emb[i];
    __syncthreads();
    int tid = blockIdx.x * blockDim.x + threadIdx.x;
    int e = tid >> 5;
    if (e >= E) return;
    int c4 = (tid & 31) << 2;
    int s = ei[e];
    int d = ei[E + e];
    int b = eattr[e * 3];
    float4 ev = *(const float4*)(bemb + b * 128 + c4);
    float4 hv = ld4(h + (size_t)s * 128 + c4);
    float4 m;
    m.x = fmaxf(hv.x + ev.x, 0.f);
    m.y = fmaxf(hv.y + ev.y, 0.f);
    m.z = fmaxf(hv.z + ev.z, 0.f);
    m.w = fmaxf(hv.w + ev.w, 0.f);
    float* ap = agg + (size_t)d * 128 + c4;
    atomAddF(ap + 0, m.x);
    atomAddF(ap + 1, m.y);
    atomAddF(ap + 2, m.z);
    atomAddF(ap + 3, m.w);
}

// z = relu((h+agg) @ W1 + b1) @ W2 + b2  — fused, t stays in LDS.
// 32 rows per block, 256 threads. z may alias agg (block-local rows only).
template <typename HT>
__global__ __launch_bounds__(256) void mlp_kernel(const HT* __restrict__ h, const float* agg,
                                                  const float* __restrict__ W1, const float* __restrict__ b1,
                                                  const float* __restrict__ W2, const float* __restrict__ b2,
                                                  float* z, int N) {
    __shared__ float xs[32][128];
    __shared__ float ts[32][256];
    int rowBase = blockIdx.x * 32;
    int tid = threadIdx.x;

    // stage x = h + agg
#pragma unroll
    for (int j = 0; j < 4; ++j) {
        int f = tid + j * 256;           // 1024 float4
        int r = f >> 5;
        int c4 = (f & 31) << 2;
        int row = rowBase + r;
        float4 v = {0.f, 0.f, 0.f, 0.f};
        if (row < N) {
            float4 hv = ld4(h + (size_t)row * 128 + c4);
            float4 av = *(const float4*)(agg + (size_t)row * 128 + c4);
            v.x = hv.x + av.x; v.y = hv.y + av.y; v.z = hv.z + av.z; v.w = hv.w + av.w;
        }
        *(float4*)(&xs[r][c4]) = v;
    }
    __syncthreads();

    // GEMM1: x(32x128) @ W1(128x256) -> relu -> ts
    {
        int tx = tid & 63;    // 64 col-groups of 4 -> 256 cols
        int ty = tid >> 6;    // 4 row-groups of 8 -> 32 rows
        int jc = tx * 4;
        int rb = ty * 8;
        float acc[8][4];
#pragma unroll
        for (int r = 0; r < 8; ++r)
#pragma unroll
            for (int c = 0; c < 4; ++c) acc[r][c] = 0.f;

        for (int kk = 0; kk < 128; kk += 4) {
            float wv[4][4];
#pragma unroll
            for (int i = 0; i < 4; ++i)
                *(float4*)wv[i] = *(const float4*)(W1 + (size_t)(kk + i) * 256 + jc);
#pragma unroll
            for (int r = 0; r < 8; ++r) {
                float xv[4];
                *(float4*)xv = *(const float4*)(&xs[rb + r][kk]);
#pragma unroll
                for (int c = 0; c < 4; ++c)
                    acc[r][c] += xv[0] * wv[0][c] + xv[1] * wv[1][c] + xv[2] * wv[2][c] + xv[3] * wv[3][c];
            }
        }
        float bv[4];
        *(float4*)bv = *(const float4*)(b1 + jc);
#pragma unroll
        for (int r = 0; r < 8; ++r) {
            float4 o;
            o.x = fmaxf(acc[r][0] + bv[0], 0.f);
            o.y = fmaxf(acc[r][1] + bv[1], 0.f);
            o.z = fmaxf(acc[r][2] + bv[2], 0.f);
            o.w = fmaxf(acc[r][3] + bv[3], 0.f);
            *(float4*)(&ts[rb + r][jc]) = o;
        }
    }
    __syncthreads();

    // GEMM2: ts(32x256) @ W2(256x128) -> z
    {
        int tx = tid & 31;    // 32 col-groups of 4 -> 128 cols
        int ty = tid >> 5;    // 8 row-groups of 4 -> 32 rows
        int jc = tx * 4;
        int rb = ty * 4;
        float acc[4][4];
#pragma unroll
        for (int r = 0; r < 4; ++r)
#pragma unroll
            for (int c = 0; c < 4; ++c) acc[r][c] = 0.f;

        for (int kk = 0; kk < 256; kk += 4) {
            float wv[4][4];
#pragma unroll
            for (int i = 0; i < 4; ++i)
                *(float4*)wv[i] = *(const float4*)(W2 + (size_t)(kk + i) * 128 + jc);
#pragma unroll
            for (int r = 0; r < 4; ++r) {
                float xv[4];
                *(float4*)xv = *(const float4*)(&ts[rb + r][kk]);
#pragma unroll
                for (int c = 0; c < 4; ++c)
                    acc[r][c] += xv[0] * wv[0][c] + xv[1] * wv[1][c] + xv[2] * wv[2][c] + xv[3] * wv[3][c];
            }
        }
        float bv[4];
        *(float4*)bv = *(const float4*)(b2 + jc);
#pragma unroll
        for (int r = 0; r < 4; ++r) {
            int row = rowBase + rb + r;
            if (row >= N) continue;
            float4 o;
            o.x = acc[r][0] + bv[0];
            o.y = acc[r][1] + bv[1];
            o.z = acc[r][2] + bv[2];
            o.w = acc[r][3] + bv[3];
            *(float4*)(z + (size_t)row * 128 + jc) = o;
        }
    }
}

// per-column sum and sumsq
__global__ void bn_reduce_kernel(const float* __restrict__ z, float* __restrict__ stats, int N) {
    int tid = threadIdx.x;
    int c = tid & 127;
    int rh = tid >> 7;
    float s = 0.f, q = 0.f;
    for (int r = blockIdx.x * 2 + rh; r < N; r += gridDim.x * 2) {
        float v = z[(size_t)r * 128 + c];
        s += v;
        q += v * v;
    }
    __shared__ float ls[256], lq[256];
    ls[tid] = s;
    lq[tid] = q;
    __syncthreads();
    if (tid < 128) {
        s = ls[tid] + ls[tid + 128];
        q = lq[tid] + lq[tid + 128];
        atomAddF(stats + c, s);
        atomAddF(stats + 128 + c, q);
    }
}

// h = maybe_relu((z - mean) * rsqrt(var+eps) * gamma + beta)
template <typename HT>
__global__ void bn_apply_kernel(const float* __restrict__ z, const float* __restrict__ stats,
                                const float* __restrict__ gamma, const float* __restrict__ beta,
                                HT* __restrict__ h, int N, float invN, int do_relu) {
    int tid = blockIdx.x * blockDim.x + threadIdx.x;
    if (tid >= N * 32) return;
    int i = tid >> 5;
    int c4 = (tid & 31) << 2;
    float4 v = *(const float4*)(z + (size_t)i * 128 + c4);
    float vv[4] = {v.x, v.y, v.z, v.w};
    float ov[4];
#pragma unroll
    for (int j = 0; j < 4; ++j) {
        int c = c4 + j;
        float mean = stats[c] * invN;
        float var = stats[128 + c] * invN - mean * mean;
        float sc = rsqrtf(var + 1e-5f) * gamma[c];
        float o = (vv[j] - mean) * sc + beta[c];
        if (do_relu) o = fmaxf(o, 0.f);
        ov[j] = o;
    }
    st4(h + (size_t)i * 128 + c4, make_float4(ov[0], ov[1], ov[2], ov[3]));
}

// out[batch[i]] += h[i]
template <typename HT>
__global__ void pool_kernel(const HT* __restrict__ h, const int* __restrict__ batch,
                            float* __restrict__ out, int N) {
    int tid = blockIdx.x * blockDim.x + threadIdx.x;
    if (tid >= N * 32) return;
    int i = tid >> 5;
    int c4 = (tid & 31) << 2;
    int g = batch[i];
    float4 v = ld4(h + (size_t)i * 128 + c4);
    float* op = out + (size_t)g * 128 + c4;
    atomAddF(op + 0, v.x);
    atomAddF(op + 1, v.y);
    atomAddF(op + 2, v.z);
    atomAddF(op + 3, v.w);
}

template <typename HT>
static void run_pipeline(const int* x, const int* ei, const int* eattr, const int* batch,
                         const float* atom_e, const float* bond_e,
                         const float* W1, const float* b1, const float* W2, const float* b2,
                         const float* gamma, const float* beta,
                         float* d_out, int out_size, void* d_ws,
                         int N, int E, hipStream_t stream) {
    char* ws = (char*)d_ws;
    HT* h = (HT*)ws;
    ws += ((size_t)N * 128 * sizeof(HT) + 255) & ~(size_t)255;
    float* agg = (float*)ws;                       // also holds z
    ws += ((size_t)N * 128 * sizeof(float) + 255) & ~(size_t)255;
    float* stats = (float*)ws;

    size_t szagg = (size_t)N * 128 * sizeof(float);
    float invN = 1.0f / (float)N;
    int nf4 = N * 32;
    int ef4 = E * 32;

    init_h_kernel<HT><<<(nf4 + 255) / 256, 256, 0, stream>>>(x, atom_e, h, N);

    for (int l = 0; l < LAYERS; ++l) {
        hipMemsetAsync(agg, 0, szagg, stream);
        edge_scatter_kernel<HT><<<(ef4 + 255) / 256, 256, 0, stream>>>(ei, eattr, bond_e, h, agg, E);
        mlp_kernel<HT><<<(N + 31) / 32, 256, 0, stream>>>(h, agg,
                                                          W1 + (size_t)l * 128 * 256, b1 + (size_t)l * 256,
                                                          W2 + (size_t)l * 256 * 128, b2 + (size_t)l * 128,
                                                          agg, N);
        hipMemsetAsync(stats, 0, 256 * sizeof(float), stream);
        bn_reduce_kernel<<<2048, 256, 0, stream>>>(agg, stats, N);
        bn_apply_kernel<HT><<<(nf4 + 255) / 256, 256, 0, stream>>>(agg, stats, gamma + (size_t)l * 128,
                                                                   beta + (size_t)l * 128, h, N, invN,
                                                                   (l < LAYERS - 1) ? 1 : 0);
    }

    hipMemsetAsync(d_out, 0, (size_t)out_size * sizeof(float), stream);
    pool_kernel<HT><<<(nf4 + 255) / 256, 256, 0, stream>>>(h, batch, d_out, N);
}

extern "C" void kernel_launch(void* const* d_in, const int* in_sizes, int n_in,
                              void* d_out, int out_size, void* d_ws, size_t ws_size,
                              hipStream_t stream) {
    const int* x        = (const int*)d_in[0];
    const int* ei       = (const int*)d_in[1];
    const int* eattr    = (const int*)d_in[2];
    const int* batch    = (const int*)d_in[3];
    const float* atom_e = (const float*)d_in[4];
    const float* bond_e = (const float*)d_in[5];
    const float* W1     = (const float*)d_in[6];
    const float* b1     = (const float*)d_in[7];
    const float* W2     = (const float*)d_in[8];
    const float* b2     = (const float*)d_in[9];
    const float* gamma  = (const float*)d_in[10];
    const float* beta   = (const float*)d_in[11];

    int N = in_sizes[0] / 9;
    int E = in_sizes[1] / 2;

    size_t need_f32 = 2 * (((size_t)N * 128 * 4 + 255) & ~(size_t)255) + 4096;
    if (ws_size >= need_f32) {
        run_pipeline<float>(x, ei, eattr, batch, atom_e, bond_e, W1, b1, W2, b2, gamma, beta,
                            (float*)d_out, out_size, d_ws, N, E, stream);
    } else {
        run_pipeline<unsigned short>(x, ei, eattr, batch, atom_e, bond_e, W1, b1, W2, b2, gamma, beta,
                                     (float*)d_out, out_size, d_ws, N, E, stream);
    }
}

// Round 3
// 4593.922 us; speedup vs baseline: 1.9580x; 1.9580x over previous
//
#include <hip/hip_runtime.h>

#define LAYERS 5

__device__ __forceinline__ void atomAddF(float* p, float v) {
    __hip_atomic_fetch_add(p, v, __ATOMIC_RELAXED, __HIP_MEMORY_SCOPE_AGENT);
}

// ---- bf16 helpers ----
__device__ __forceinline__ float b2f(unsigned short u) { return __uint_as_float(((unsigned)u) << 16); }
__device__ __forceinline__ unsigned short f2b(float f) {
    unsigned int x = __float_as_uint(f);
    x += 0x7fff + ((x >> 16) & 1);   // round-to-nearest-even
    return (unsigned short)(x >> 16);
}
__device__ __forceinline__ float4 ld4(const unsigned short* p) {
    ushort4 u = *(const ushort4*)p;
    return make_float4(b2f(u.x), b2f(u.y), b2f(u.z), b2f(u.w));
}
__device__ __forceinline__ void st4(unsigned short* p, float4 v) {
    ushort4 u;
    u.x = f2b(v.x); u.y = f2b(v.y); u.z = f2b(v.z); u.w = f2b(v.w);
    *(ushort4*)p = u;
}

// h[i] = atom_emb[x[i*9]]  (bf16 store)
__global__ void init_h_kernel(const int* __restrict__ x, const float* __restrict__ atom_emb,
                              unsigned short* __restrict__ h, int N) {
    int tid = blockIdx.x * blockDim.x + threadIdx.x;
    if (tid >= N * 32) return;
    int i = tid >> 5;
    int c4 = (tid & 31) << 2;
    int a = x[i * 9];
    float4 v = *(const float4*)(atom_emb + a * 128 + c4);
    st4(h + (size_t)i * 128 + c4, v);
}

// ---------------- CSR build (once per call) ----------------
__global__ void hist_kernel(const int* __restrict__ ei, int* __restrict__ cnt, int E) {
    int e = blockIdx.x * blockDim.x + threadIdx.x;
    if (e < E) atomicAdd(&cnt[ei[E + e]], 1);
}

// per-block (1024-item) sums of cnt
__global__ void scan_block_sum(const int* __restrict__ cnt, int* __restrict__ bsum, int N) {
    __shared__ int ls[256];
    int base = blockIdx.x * 1024;
    int tid = threadIdx.x;
    int s = 0;
#pragma unroll
    for (int j = 0; j < 4; ++j) {
        int i = base + tid * 4 + j;
        if (i < N) s += cnt[i];
    }
    ls[tid] = s;
    __syncthreads();
    for (int off = 128; off > 0; off >>= 1) {
        if (tid < off) ls[tid] += ls[tid + off];
        __syncthreads();
    }
    if (tid == 0) bsum[blockIdx.x] = ls[0];
}

// serial exclusive scan of block sums (nb ~ 293, once per call)
__global__ void scan_bsums(int* __restrict__ bsum, int nb) {
    if (blockIdx.x == 0 && threadIdx.x == 0) {
        int acc = 0;
        for (int i = 0; i < nb; ++i) { int v = bsum[i]; bsum[i] = acc; acc += v; }
    }
}

// write rowptr (exclusive prefix) and init cursor = rowptr.
// NOTE: cnt aliases cursor — each index is read (v[j]) before being overwritten by the same thread.
__global__ void scan_write(int* __restrict__ cnt_cursor, const int* __restrict__ bsum,
                           int* __restrict__ rowptr, int N, int E) {
    __shared__ int ls[256];
    int base = blockIdx.x * 1024;
    int tid = threadIdx.x;
    int v[4];
    int s = 0;
#pragma unroll
    for (int j = 0; j < 4; ++j) {
        int i = base + tid * 4 + j;
        v[j] = (i < N) ? cnt_cursor[i] : 0;
        s += v[j];
    }
    ls[tid] = s;
    __syncthreads();
    if (tid == 0) {
        int acc = 0;
        for (int i = 0; i < 256; ++i) { int t = ls[i]; ls[i] = acc; acc += t; }
    }
    __syncthreads();
    int off = bsum[blockIdx.x] + ls[tid];
#pragma unroll
    for (int j = 0; j < 4; ++j) {
        int i = base + tid * 4 + j;
        if (i < N) {
            rowptr[i] = off;
            cnt_cursor[i] = off;
            off += v[j];
        }
    }
    if (blockIdx.x == 0 && tid == 0) rowptr[N] = E;
}

// ebuf[pos] = src | bond<<24   (src < 2^24, bond < 8)
__global__ void scatter_kernel(const int* __restrict__ ei, const int* __restrict__ eattr,
                               int* __restrict__ cursor, int* __restrict__ ebuf, int E) {
    int e = blockIdx.x * blockDim.x + threadIdx.x;
    if (e >= E) return;
    int d = ei[E + e];
    int pos = atomicAdd(&cursor[d], 1);
    ebuf[pos] = ei[e] | (eattr[e * 3] << 24);
}

// ---------------- per-layer kernels ----------------
// agg[n] = sum over in-edges of relu(h[src] + bond_emb[bond]); one wave per node.
__global__ __launch_bounds__(256) void agg_gather_kernel(const int* __restrict__ rowptr,
                                                         const int* __restrict__ ebuf,
                                                         const float* __restrict__ bond_emb,
                                                         const unsigned short* __restrict__ h,
                                                         float* __restrict__ agg, int N) {
    __shared__ float bemb[8 * 128];
    for (int i = threadIdx.x; i < 8 * 128; i += blockDim.x) bemb[i] = bond_emb[i];
    __syncthreads();
    int wid = (blockIdx.x * blockDim.x + threadIdx.x) >> 6;
    if (wid >= N) return;
    int lane = threadIdx.x & 63;
    int c2 = lane * 2;
    int beg = rowptr[wid], end = rowptr[wid + 1];
    float a0 = 0.f, a1 = 0.f;
    for (int j = beg; j < end; ++j) {
        int ee = ebuf[j];
        int s = ee & 0xFFFFFF;
        int b = ee >> 24;
        ushort2 u = *(const ushort2*)(h + (size_t)s * 128 + c2);
        a0 += fmaxf(b2f(u.x) + bemb[b * 128 + c2], 0.f);
        a1 += fmaxf(b2f(u.y) + bemb[b * 128 + c2 + 1], 0.f);
    }
    *(float2*)(agg + (size_t)wid * 128 + c2) = make_float2(a0, a1);
}

// z = relu((h+agg) @ W1 + b1) @ W2 + b2  — fused, t stays in LDS. z may alias agg.
__global__ __launch_bounds__(256) void mlp_kernel(const unsigned short* __restrict__ h, const float* agg,
                                                  const float* __restrict__ W1, const float* __restrict__ b1,
                                                  const float* __restrict__ W2, const float* __restrict__ b2,
                                                  float* z, int N) {
    __shared__ float xs[32][128];
    __shared__ float ts[32][256];
    int rowBase = blockIdx.x * 32;
    int tid = threadIdx.x;

#pragma unroll
    for (int j = 0; j < 4; ++j) {
        int f = tid + j * 256;
        int r = f >> 5;
        int c4 = (f & 31) << 2;
        int row = rowBase + r;
        float4 v = {0.f, 0.f, 0.f, 0.f};
        if (row < N) {
            float4 hv = ld4(h + (size_t)row * 128 + c4);
            float4 av = *(const float4*)(agg + (size_t)row * 128 + c4);
            v.x = hv.x + av.x; v.y = hv.y + av.y; v.z = hv.z + av.z; v.w = hv.w + av.w;
        }
        *(float4*)(&xs[r][c4]) = v;
    }
    __syncthreads();

    {
        int tx = tid & 63;
        int ty = tid >> 6;
        int jc = tx * 4;
        int rb = ty * 8;
        float acc[8][4];
#pragma unroll
        for (int r = 0; r < 8; ++r)
#pragma unroll
            for (int c = 0; c < 4; ++c) acc[r][c] = 0.f;

        for (int kk = 0; kk < 128; kk += 4) {
            float wv[4][4];
#pragma unroll
            for (int i = 0; i < 4; ++i)
                *(float4*)wv[i] = *(const float4*)(W1 + (size_t)(kk + i) * 256 + jc);
#pragma unroll
            for (int r = 0; r < 8; ++r) {
                float xv[4];
                *(float4*)xv = *(const float4*)(&xs[rb + r][kk]);
#pragma unroll
                for (int c = 0; c < 4; ++c)
                    acc[r][c] += xv[0] * wv[0][c] + xv[1] * wv[1][c] + xv[2] * wv[2][c] + xv[3] * wv[3][c];
            }
        }
        float bv[4];
        *(float4*)bv = *(const float4*)(b1 + jc);
#pragma unroll
        for (int r = 0; r < 8; ++r) {
            float4 o;
            o.x = fmaxf(acc[r][0] + bv[0], 0.f);
            o.y = fmaxf(acc[r][1] + bv[1], 0.f);
            o.z = fmaxf(acc[r][2] + bv[2], 0.f);
            o.w = fmaxf(acc[r][3] + bv[3], 0.f);
            *(float4*)(&ts[rb + r][jc]) = o;
        }
    }
    __syncthreads();

    {
        int tx = tid & 31;
        int ty = tid >> 5;
        int jc = tx * 4;
        int rb = ty * 4;
        float acc[4][4];
#pragma unroll
        for (int r = 0; r < 4; ++r)
#pragma unroll
            for (int c = 0; c < 4; ++c) acc[r][c] = 0.f;

        for (int kk = 0; kk < 256; kk += 4) {
            float wv[4][4];
#pragma unroll
            for (int i = 0; i < 4; ++i)
                *(float4*)wv[i] = *(const float4*)(W2 + (size_t)(kk + i) * 128 + jc);
#pragma unroll
            for (int r = 0; r < 4; ++r) {
                float xv[4];
                *(float4*)xv = *(const float4*)(&ts[rb + r][kk]);
#pragma unroll
                for (int c = 0; c < 4; ++c)
                    acc[r][c] += xv[0] * wv[0][c] + xv[1] * wv[1][c] + xv[2] * wv[2][c] + xv[3] * wv[3][c];
            }
        }
        float bv[4];
        *(float4*)bv = *(const float4*)(b2 + jc);
#pragma unroll
        for (int r = 0; r < 4; ++r) {
            int row = rowBase + rb + r;
            if (row >= N) continue;
            float4 o;
            o.x = acc[r][0] + bv[0];
            o.y = acc[r][1] + bv[1];
            o.z = acc[r][2] + bv[2];
            o.w = acc[r][3] + bv[3];
            *(float4*)(z + (size_t)row * 128 + jc) = o;
        }
    }
}

__global__ void bn_reduce_kernel(const float* __restrict__ z, float* __restrict__ stats, int N) {
    int tid = threadIdx.x;
    int c = tid & 127;
    int rh = tid >> 7;
    float s = 0.f, q = 0.f;
    for (int r = blockIdx.x * 2 + rh; r < N; r += gridDim.x * 2) {
        float v = z[(size_t)r * 128 + c];
        s += v;
        q += v * v;
    }
    __shared__ float ls[256], lq[256];
    ls[tid] = s;
    lq[tid] = q;
    __syncthreads();
    if (tid < 128) {
        s = ls[tid] + ls[tid + 128];
        q = lq[tid] + lq[tid + 128];
        atomAddF(stats + c, s);
        atomAddF(stats + 128 + c, q);
    }
}

__global__ void bn_apply_kernel(const float* __restrict__ z, const float* __restrict__ stats,
                                const float* __restrict__ gamma, const float* __restrict__ beta,
                                unsigned short* __restrict__ h, int N, float invN, int do_relu) {
    int tid = blockIdx.x * blockDim.x + threadIdx.x;
    if (tid >= N * 32) return;
    int i = tid >> 5;
    int c4 = (tid & 31) << 2;
    float4 v = *(const float4*)(z + (size_t)i * 128 + c4);
    float vv[4] = {v.x, v.y, v.z, v.w};
    float ov[4];
#pragma unroll
    for (int j = 0; j < 4; ++j) {
        int c = c4 + j;
        float mean = stats[c] * invN;
        float var = stats[128 + c] * invN - mean * mean;
        float sc = rsqrtf(var + 1e-5f) * gamma[c];
        float o = (vv[j] - mean) * sc + beta[c];
        if (do_relu) o = fmaxf(o, 0.f);
        ov[j] = o;
    }
    st4(h + (size_t)i * 128 + c4, make_float4(ov[0], ov[1], ov[2], ov[3]));
}

__global__ void pool_kernel(const unsigned short* __restrict__ h, const int* __restrict__ batch,
                            float* __restrict__ out, int N) {
    int tid = blockIdx.x * blockDim.x + threadIdx.x;
    if (tid >= N * 32) return;
    int i = tid >> 5;
    int c4 = (tid & 31) << 2;
    int g = batch[i];
    float4 v = ld4(h + (size_t)i * 128 + c4);
    float* op = out + (size_t)g * 128 + c4;
    atomAddF(op + 0, v.x);
    atomAddF(op + 1, v.y);
    atomAddF(op + 2, v.z);
    atomAddF(op + 3, v.w);
}

extern "C" void kernel_launch(void* const* d_in, const int* in_sizes, int n_in,
                              void* d_out, int out_size, void* d_ws, size_t ws_size,
                              hipStream_t stream) {
    const int* x        = (const int*)d_in[0];
    const int* ei       = (const int*)d_in[1];
    const int* eattr    = (const int*)d_in[2];
    const int* batch    = (const int*)d_in[3];
    const float* atom_e = (const float*)d_in[4];
    const float* bond_e = (const float*)d_in[5];
    const float* W1     = (const float*)d_in[6];
    const float* b1     = (const float*)d_in[7];
    const float* W2     = (const float*)d_in[8];
    const float* b2     = (const float*)d_in[9];
    const float* gamma  = (const float*)d_in[10];
    const float* beta   = (const float*)d_in[11];

    int N = in_sizes[0] / 9;
    int E = in_sizes[1] / 2;

    auto align = [](size_t v) { return (v + 255) & ~(size_t)255; };
    char* ws = (char*)d_ws;
    unsigned short* h = (unsigned short*)ws; ws += align((size_t)N * 128 * 2);
    float* agg   = (float*)ws;               ws += align((size_t)N * 128 * 4);   // also z
    int* rowptr  = (int*)ws;                 ws += align((size_t)(N + 1) * 4);
    int* cursor  = (int*)ws;                 ws += align((size_t)N * 4);          // also cnt
    int* ebuf    = (int*)ws;                 ws += align((size_t)E * 4);
    int* bsum    = (int*)ws;                 ws += align((size_t)4096 * 4);
    float* stats = (float*)ws;

    float invN = 1.0f / (float)N;
    int nf4 = N * 32;
    int nb = (N + 1023) / 1024;

    init_h_kernel<<<(nf4 + 255) / 256, 256, 0, stream>>>(x, atom_e, h, N);

    // CSR build (once per call)
    hipMemsetAsync(cursor, 0, (size_t)N * 4, stream);
    hist_kernel<<<(E + 255) / 256, 256, 0, stream>>>(ei, cursor, E);
    scan_block_sum<<<nb, 256, 0, stream>>>(cursor, bsum, N);
    scan_bsums<<<1, 64, 0, stream>>>(bsum, nb);
    scan_write<<<nb, 256, 0, stream>>>(cursor, bsum, rowptr, N, E);
    scatter_kernel<<<(E + 255) / 256, 256, 0, stream>>>(ei, eattr, cursor, ebuf, E);

    for (int l = 0; l < LAYERS; ++l) {
        agg_gather_kernel<<<(N * 64 + 255) / 256, 256, 0, stream>>>(rowptr, ebuf, bond_e, h, agg, N);
        mlp_kernel<<<(N + 31) / 32, 256, 0, stream>>>(h, agg,
                                                      W1 + (size_t)l * 128 * 256, b1 + (size_t)l * 256,
                                                      W2 + (size_t)l * 256 * 128, b2 + (size_t)l * 128,
                                                      agg, N);
        hipMemsetAsync(stats, 0, 256 * sizeof(float), stream);
        bn_reduce_kernel<<<2048, 256, 0, stream>>>(agg, stats, N);
        bn_apply_kernel<<<(nf4 + 255) / 256, 256, 0, stream>>>(agg, stats, gamma + (size_t)l * 128,
                                                               beta + (size_t)l * 128, h, N, invN,
                                                               (l < LAYERS - 1) ? 1 : 0);
    }

    hipMemsetAsync(d_out, 0, (size_t)out_size * sizeof(float), stream);
    pool_kernel<<<(nf4 + 255) / 256, 256, 0, stream>>>(h, batch, (float*)d_out, N);
}

// Round 4
// 2289.871 us; speedup vs baseline: 3.9281x; 2.0062x over previous
//
#include <hip/hip_runtime.h>

#define LAYERS 5

typedef __attribute__((ext_vector_type(8))) short short8v;
typedef __attribute__((ext_vector_type(4))) float f32x4;

#define MFMA(a, b, c) __builtin_amdgcn_mfma_f32_16x16x32_bf16(a, b, c, 0, 0, 0)

__device__ __forceinline__ void atomAddF(float* p, float v) {
    __hip_atomic_fetch_add(p, v, __ATOMIC_RELAXED, __HIP_MEMORY_SCOPE_AGENT);
}

// ---- bf16 helpers ----
__device__ __forceinline__ float b2f(unsigned short u) { return __uint_as_float(((unsigned)u) << 16); }
__device__ __forceinline__ unsigned short f2b(float f) {
    unsigned int x = __float_as_uint(f);
    x += 0x7fff + ((x >> 16) & 1);
    return (unsigned short)(x >> 16);
}
__device__ __forceinline__ float4 ld4(const unsigned short* p) {
    ushort4 u = *(const ushort4*)p;
    return make_float4(b2f(u.x), b2f(u.y), b2f(u.z), b2f(u.w));
}
__device__ __forceinline__ void st4(unsigned short* p, float4 v) {
    ushort4 u;
    u.x = f2b(v.x); u.y = f2b(v.y); u.z = f2b(v.z); u.w = f2b(v.w);
    *(ushort4*)p = u;
}

// h[i] = atom_emb[x[i*9]]  (bf16 store)
__global__ void init_h_kernel(const int* __restrict__ x, const float* __restrict__ atom_emb,
                              unsigned short* __restrict__ h, int N) {
    int tid = blockIdx.x * blockDim.x + threadIdx.x;
    if (tid >= N * 32) return;
    int i = tid >> 5;
    int c4 = (tid & 31) << 2;
    int a = x[i * 9];
    float4 v = *(const float4*)(atom_emb + a * 128 + c4);
    st4(h + (size_t)i * 128 + c4, v);
}

// ---------------- CSR build (once per call) ----------------
__global__ void hist_kernel(const int* __restrict__ ei, int* __restrict__ cnt, int E) {
    int e = blockIdx.x * blockDim.x + threadIdx.x;
    if (e < E) atomicAdd(&cnt[ei[E + e]], 1);
}

__global__ void scan_block_sum(const int* __restrict__ cnt, int* __restrict__ bsum, int N) {
    __shared__ int ls[256];
    int base = blockIdx.x * 1024;
    int tid = threadIdx.x;
    int s = 0;
#pragma unroll
    for (int j = 0; j < 4; ++j) {
        int i = base + tid * 4 + j;
        if (i < N) s += cnt[i];
    }
    ls[tid] = s;
    __syncthreads();
    for (int off = 128; off > 0; off >>= 1) {
        if (tid < off) ls[tid] += ls[tid + off];
        __syncthreads();
    }
    if (tid == 0) bsum[blockIdx.x] = ls[0];
}

__global__ void scan_bsums(int* __restrict__ bsum, int nb) {
    if (blockIdx.x == 0 && threadIdx.x == 0) {
        int acc = 0;
        for (int i = 0; i < nb; ++i) { int v = bsum[i]; bsum[i] = acc; acc += v; }
    }
}

__global__ void scan_write(int* __restrict__ cnt_cursor, const int* __restrict__ bsum,
                           int* __restrict__ rowptr, int N, int E) {
    __shared__ int ls[256];
    int base = blockIdx.x * 1024;
    int tid = threadIdx.x;
    int v[4];
    int s = 0;
#pragma unroll
    for (int j = 0; j < 4; ++j) {
        int i = base + tid * 4 + j;
        v[j] = (i < N) ? cnt_cursor[i] : 0;
        s += v[j];
    }
    ls[tid] = s;
    __syncthreads();
    if (tid == 0) {
        int acc = 0;
        for (int i = 0; i < 256; ++i) { int t = ls[i]; ls[i] = acc; acc += t; }
    }
    __syncthreads();
    int off = bsum[blockIdx.x] + ls[tid];
#pragma unroll
    for (int j = 0; j < 4; ++j) {
        int i = base + tid * 4 + j;
        if (i < N) {
            rowptr[i] = off;
            cnt_cursor[i] = off;
            off += v[j];
        }
    }
    if (blockIdx.x == 0 && tid == 0) rowptr[N] = E;
}

__global__ void scatter_kernel(const int* __restrict__ ei, const int* __restrict__ eattr,
                               int* __restrict__ cursor, int* __restrict__ ebuf, int E) {
    int e = blockIdx.x * blockDim.x + threadIdx.x;
    if (e >= E) return;
    int d = ei[E + e];
    int pos = atomicAdd(&cursor[d], 1);
    ebuf[pos] = ei[e] | (eattr[e * 3] << 24);
}

// ---------------- weight pre-pack (hi/lo bf16, fragment order) ----------------
// W1f[l][nt(16)][ks(4)][lane(64)][j(8)]: value = W1[l][k=ks*32+(lane>>4)*8+j][n=nt*16+(lane&15)]
__global__ void pack_w1_kernel(const float* __restrict__ W1,
                               unsigned short* __restrict__ wh, unsigned short* __restrict__ wl) {
    int tid = blockIdx.x * blockDim.x + threadIdx.x;
    if (tid >= LAYERS * 16 * 4 * 64) return;
    int lane = tid & 63;
    int ks = (tid >> 6) & 3;
    int nt = (tid >> 8) & 15;
    int l  = tid >> 12;
    int n  = nt * 16 + (lane & 15);
    int k0 = ks * 32 + ((lane >> 4) << 3);
    unsigned short hh[8], ll[8];
#pragma unroll
    for (int j = 0; j < 8; ++j) {
        float v = W1[((size_t)l * 128 + k0 + j) * 256 + n];
        hh[j] = f2b(v);
        ll[j] = f2b(v - b2f(hh[j]));
    }
    size_t off = (size_t)tid * 8;
    *(ushort4*)(wh + off)     = make_ushort4(hh[0], hh[1], hh[2], hh[3]);
    *(ushort4*)(wh + off + 4) = make_ushort4(hh[4], hh[5], hh[6], hh[7]);
    *(ushort4*)(wl + off)     = make_ushort4(ll[0], ll[1], ll[2], ll[3]);
    *(ushort4*)(wl + off + 4) = make_ushort4(ll[4], ll[5], ll[6], ll[7]);
}

// W2f[l][nt(8)][ks(8)][lane(64)][j(8)]: value = W2[l][k=ks*32+(lane>>4)*8+j][n=nt*16+(lane&15)]
__global__ void pack_w2_kernel(const float* __restrict__ W2,
                               unsigned short* __restrict__ wh, unsigned short* __restrict__ wl) {
    int tid = blockIdx.x * blockDim.x + threadIdx.x;
    if (tid >= LAYERS * 8 * 8 * 64) return;
    int lane = tid & 63;
    int ks = (tid >> 6) & 7;
    int nt = (tid >> 9) & 7;
    int l  = tid >> 12;
    int n  = nt * 16 + (lane & 15);
    int k0 = ks * 32 + ((lane >> 4) << 3);
    unsigned short hh[8], ll[8];
#pragma unroll
    for (int j = 0; j < 8; ++j) {
        float v = W2[((size_t)l * 256 + k0 + j) * 128 + n];
        hh[j] = f2b(v);
        ll[j] = f2b(v - b2f(hh[j]));
    }
    size_t off = (size_t)tid * 8;
    *(ushort4*)(wh + off)     = make_ushort4(hh[0], hh[1], hh[2], hh[3]);
    *(ushort4*)(wh + off + 4) = make_ushort4(hh[4], hh[5], hh[6], hh[7]);
    *(ushort4*)(wl + off)     = make_ushort4(ll[0], ll[1], ll[2], ll[3]);
    *(ushort4*)(wl + off + 4) = make_ushort4(ll[4], ll[5], ll[6], ll[7]);
}

// ---------------- per-layer kernels ----------------
// agg[n] = sum over in-edges of relu(h[src] + bond_emb[bond]); one wave per node.
__global__ __launch_bounds__(256) void agg_gather_kernel(const int* __restrict__ rowptr,
                                                         const int* __restrict__ ebuf,
                                                         const float* __restrict__ bond_emb,
                                                         const unsigned short* __restrict__ h,
                                                         float* __restrict__ agg, int N) {
    __shared__ float bemb[8 * 128];
    for (int i = threadIdx.x; i < 8 * 128; i += blockDim.x) bemb[i] = bond_emb[i];
    __syncthreads();
    int wid = (blockIdx.x * blockDim.x + threadIdx.x) >> 6;
    if (wid >= N) return;
    int lane = threadIdx.x & 63;
    int c2 = lane * 2;
    int beg = rowptr[wid], end = rowptr[wid + 1];
    float a0 = 0.f, a1 = 0.f;
    for (int j = beg; j < end; ++j) {
        int ee = ebuf[j];
        int s = ee & 0xFFFFFF;
        int b = ee >> 24;
        ushort2 u = *(const ushort2*)(h + (size_t)s * 128 + c2);
        a0 += fmaxf(b2f(u.x) + bemb[b * 128 + c2], 0.f);
        a1 += fmaxf(b2f(u.y) + bemb[b * 128 + c2 + 1], 0.f);
    }
    *(float2*)(agg + (size_t)wid * 128 + c2) = make_float2(a0, a1);
}

// z = relu((h+agg)@W1 + b1)@W2 + b2 — split-bf16 MFMA, t in LDS. z may alias agg.
__global__ __launch_bounds__(256) void mlp_mfma_kernel(const unsigned short* __restrict__ h,
                                                       const float* agg,
                                                       const unsigned short* __restrict__ w1h,
                                                       const unsigned short* __restrict__ w1l,
                                                       const unsigned short* __restrict__ w2h,
                                                       const unsigned short* __restrict__ w2l,
                                                       const float* __restrict__ b1,
                                                       const float* __restrict__ b2,
                                                       float* z, int N) {
    __shared__ unsigned short xs_h[32][136], xs_l[32][136];
    __shared__ unsigned short ts_h[32][264], ts_l[32][264];
    int tid = threadIdx.x;
    int rowBase = blockIdx.x * 32;

    // stage x = h + agg, split into hi/lo bf16
#pragma unroll
    for (int j = 0; j < 2; ++j) {
        int chunk = tid + j * 256;      // 512 chunks = 32 rows x 16
        int r = chunk >> 4;
        int c8 = (chunk & 15) << 3;
        int row = rowBase + r;
        float xv[8];
        if (row < N) {
            const unsigned short* hp = h + (size_t)row * 128 + c8;
            const float* ap = agg + (size_t)row * 128 + c8;
            float4 a0 = *(const float4*)(ap);
            float4 a1 = *(const float4*)(ap + 4);
            ushort4 u0 = *(const ushort4*)(hp);
            ushort4 u1 = *(const ushort4*)(hp + 4);
            xv[0] = b2f(u0.x) + a0.x; xv[1] = b2f(u0.y) + a0.y;
            xv[2] = b2f(u0.z) + a0.z; xv[3] = b2f(u0.w) + a0.w;
            xv[4] = b2f(u1.x) + a1.x; xv[5] = b2f(u1.y) + a1.y;
            xv[6] = b2f(u1.z) + a1.z; xv[7] = b2f(u1.w) + a1.w;
        } else {
#pragma unroll
            for (int i = 0; i < 8; ++i) xv[i] = 0.f;
        }
        unsigned short hh[8], ll[8];
#pragma unroll
        for (int i = 0; i < 8; ++i) {
            hh[i] = f2b(xv[i]);
            ll[i] = f2b(xv[i] - b2f(hh[i]));
        }
        *(ushort4*)(&xs_h[r][c8])     = make_ushort4(hh[0], hh[1], hh[2], hh[3]);
        *(ushort4*)(&xs_h[r][c8 + 4]) = make_ushort4(hh[4], hh[5], hh[6], hh[7]);
        *(ushort4*)(&xs_l[r][c8])     = make_ushort4(ll[0], ll[1], ll[2], ll[3]);
        *(ushort4*)(&xs_l[r][c8 + 4]) = make_ushort4(ll[4], ll[5], ll[6], ll[7]);
    }
    __syncthreads();

    int wv = tid >> 6;
    int lane = tid & 63;
    int lrow = lane & 15;
    int lk8 = (lane >> 4) << 3;
    int rgrp = (lane >> 4) << 2;

    // GEMM1: t[32][256] = x[32][128] @ W1
    f32x4 acc[2][4];
#pragma unroll
    for (int mt = 0; mt < 2; ++mt)
#pragma unroll
        for (int t = 0; t < 4; ++t) acc[mt][t] = (f32x4){0.f, 0.f, 0.f, 0.f};

#pragma unroll
    for (int ks = 0; ks < 4; ++ks) {
        int kb = ks * 32 + lk8;
        short8v ah0 = *(const short8v*)(&xs_h[lrow][kb]);
        short8v al0 = *(const short8v*)(&xs_l[lrow][kb]);
        short8v ah1 = *(const short8v*)(&xs_h[16 + lrow][kb]);
        short8v al1 = *(const short8v*)(&xs_l[16 + lrow][kb]);
#pragma unroll
        for (int t = 0; t < 4; ++t) {
            int nt = wv * 4 + t;
            size_t off = ((size_t)(nt * 4 + ks) * 64 + lane) * 8;
            short8v wh = *(const short8v*)(w1h + off);
            short8v wl = *(const short8v*)(w1l + off);
            acc[0][t] = MFMA(al0, wh, acc[0][t]);
            acc[0][t] = MFMA(ah0, wl, acc[0][t]);
            acc[0][t] = MFMA(ah0, wh, acc[0][t]);
            acc[1][t] = MFMA(al1, wh, acc[1][t]);
            acc[1][t] = MFMA(ah1, wl, acc[1][t]);
            acc[1][t] = MFMA(ah1, wh, acc[1][t]);
        }
    }

    // epilogue G1: t = relu(acc + b1) -> ts hi/lo
#pragma unroll
    for (int t = 0; t < 4; ++t) {
        int col = (wv * 4 + t) * 16 + lrow;
        float bb = b1[col];
#pragma unroll
        for (int mt = 0; mt < 2; ++mt) {
            int row0 = mt * 16 + rgrp;
#pragma unroll
            for (int r = 0; r < 4; ++r) {
                float tv = fmaxf(acc[mt][t][r] + bb, 0.f);
                unsigned short th = f2b(tv);
                ts_h[row0 + r][col] = th;
                ts_l[row0 + r][col] = f2b(tv - b2f(th));
            }
        }
    }
    __syncthreads();

    // GEMM2: z[32][128] = t[32][256] @ W2
    f32x4 acc2[2][2];
#pragma unroll
    for (int mt = 0; mt < 2; ++mt)
#pragma unroll
        for (int t = 0; t < 2; ++t) acc2[mt][t] = (f32x4){0.f, 0.f, 0.f, 0.f};

#pragma unroll
    for (int ks = 0; ks < 8; ++ks) {
        int kb = ks * 32 + lk8;
        short8v ah0 = *(const short8v*)(&ts_h[lrow][kb]);
        short8v al0 = *(const short8v*)(&ts_l[lrow][kb]);
        short8v ah1 = *(const short8v*)(&ts_h[16 + lrow][kb]);
        short8v al1 = *(const short8v*)(&ts_l[16 + lrow][kb]);
#pragma unroll
        for (int t = 0; t < 2; ++t) {
            int nt = wv * 2 + t;
            size_t off = ((size_t)(nt * 8 + ks) * 64 + lane) * 8;
            short8v wh = *(const short8v*)(w2h + off);
            short8v wl = *(const short8v*)(w2l + off);
            acc2[0][t] = MFMA(al0, wh, acc2[0][t]);
            acc2[0][t] = MFMA(ah0, wl, acc2[0][t]);
            acc2[0][t] = MFMA(ah0, wh, acc2[0][t]);
            acc2[1][t] = MFMA(al1, wh, acc2[1][t]);
            acc2[1][t] = MFMA(ah1, wl, acc2[1][t]);
            acc2[1][t] = MFMA(ah1, wh, acc2[1][t]);
        }
    }

    // epilogue G2: z = acc2 + b2
#pragma unroll
    for (int t = 0; t < 2; ++t) {
        int col = (wv * 2 + t) * 16 + lrow;
        float bb = b2[col];
#pragma unroll
        for (int mt = 0; mt < 2; ++mt) {
            int row0 = rowBase + mt * 16 + rgrp;
#pragma unroll
            for (int r = 0; r < 4; ++r) {
                int row = row0 + r;
                if (row < N) z[(size_t)row * 128 + col] = acc2[mt][t][r] + bb;
            }
        }
    }
}

__global__ void bn_reduce_kernel(const float* __restrict__ z, float* __restrict__ stats, int N) {
    int tid = threadIdx.x;
    int c = tid & 127;
    int rh = tid >> 7;
    float s = 0.f, q = 0.f;
    for (int r = blockIdx.x * 2 + rh; r < N; r += gridDim.x * 2) {
        float v = z[(size_t)r * 128 + c];
        s += v;
        q += v * v;
    }
    __shared__ float ls[256], lq[256];
    ls[tid] = s;
    lq[tid] = q;
    __syncthreads();
    if (tid < 128) {
        s = ls[tid] + ls[tid + 128];
        q = lq[tid] + lq[tid + 128];
        atomAddF(stats + c, s);
        atomAddF(stats + 128 + c, q);
    }
}

__global__ void bn_apply_kernel(const float* __restrict__ z, const float* __restrict__ stats,
                                const float* __restrict__ gamma, const float* __restrict__ beta,
                                unsigned short* __restrict__ h, int N, float invN, int do_relu) {
    int tid = blockIdx.x * blockDim.x + threadIdx.x;
    if (tid >= N * 32) return;
    int i = tid >> 5;
    int c4 = (tid & 31) << 2;
    float4 v = *(const float4*)(z + (size_t)i * 128 + c4);
    float vv[4] = {v.x, v.y, v.z, v.w};
    float ov[4];
#pragma unroll
    for (int j = 0; j < 4; ++j) {
        int c = c4 + j;
        float mean = stats[c] * invN;
        float var = stats[128 + c] * invN - mean * mean;
        float sc = rsqrtf(var + 1e-5f) * gamma[c];
        float o = (vv[j] - mean) * sc + beta[c];
        if (do_relu) o = fmaxf(o, 0.f);
        ov[j] = o;
    }
    st4(h + (size_t)i * 128 + c4, make_float4(ov[0], ov[1], ov[2], ov[3]));
}

// segmented pool over sorted batch: one wave per graph, no atomics.
__global__ __launch_bounds__(256) void pool_seg_kernel(const unsigned short* __restrict__ h,
                                                       const int* __restrict__ batch,
                                                       float* __restrict__ out, int N, int G) {
    int g = blockIdx.x * 4 + (threadIdx.x >> 6);
    if (g >= G) return;
    int lane = threadIdx.x & 63;
    int lo = 0, hi = N;
    while (lo < hi) { int m = (lo + hi) >> 1; if (batch[m] < g) lo = m + 1; else hi = m; }
    int s = lo;
    hi = N;
    while (lo < hi) { int m = (lo + hi) >> 1; if (batch[m] < g + 1) lo = m + 1; else hi = m; }
    int e = lo;
    int c2 = lane * 2;
    float a0 = 0.f, a1 = 0.f;
    for (int i = s; i < e; ++i) {
        ushort2 u = *(const ushort2*)(h + (size_t)i * 128 + c2);
        a0 += b2f(u.x);
        a1 += b2f(u.y);
    }
    *(float2*)(out + (size_t)g * 128 + c2) = make_float2(a0, a1);
}

extern "C" void kernel_launch(void* const* d_in, const int* in_sizes, int n_in,
                              void* d_out, int out_size, void* d_ws, size_t ws_size,
                              hipStream_t stream) {
    const int* x        = (const int*)d_in[0];
    const int* ei       = (const int*)d_in[1];
    const int* eattr    = (const int*)d_in[2];
    const int* batch    = (const int*)d_in[3];
    const float* atom_e = (const float*)d_in[4];
    const float* bond_e = (const float*)d_in[5];
    const float* W1     = (const float*)d_in[6];
    const float* b1     = (const float*)d_in[7];
    const float* W2     = (const float*)d_in[8];
    const float* b2     = (const float*)d_in[9];
    const float* gamma  = (const float*)d_in[10];
    const float* beta   = (const float*)d_in[11];

    int N = in_sizes[0] / 9;
    int E = in_sizes[1] / 2;
    int G = out_size / 128;

    auto align = [](size_t v) { return (v + 255) & ~(size_t)255; };
    char* ws = (char*)d_ws;
    unsigned short* h = (unsigned short*)ws; ws += align((size_t)N * 128 * 2);
    float* agg   = (float*)ws;               ws += align((size_t)N * 128 * 4);   // also z
    int* rowptr  = (int*)ws;                 ws += align((size_t)(N + 1) * 4);
    int* cursor  = (int*)ws;                 ws += align((size_t)N * 4);
    int* ebuf    = (int*)ws;                 ws += align((size_t)E * 4);
    int* bsum    = (int*)ws;                 ws += align((size_t)4096 * 4);
    unsigned short* w1h = (unsigned short*)ws; ws += align((size_t)LAYERS * 32768 * 2);
    unsigned short* w1l = (unsigned short*)ws; ws += align((size_t)LAYERS * 32768 * 2);
    unsigned short* w2h = (unsigned short*)ws; ws += align((size_t)LAYERS * 32768 * 2);
    unsigned short* w2l = (unsigned short*)ws; ws += align((size_t)LAYERS * 32768 * 2);
    float* stats = (float*)ws;

    float invN = 1.0f / (float)N;
    int nf4 = N * 32;
    int nb = (N + 1023) / 1024;

    init_h_kernel<<<(nf4 + 255) / 256, 256, 0, stream>>>(x, atom_e, h, N);

    // CSR build (once per call)
    hipMemsetAsync(cursor, 0, (size_t)N * 4, stream);
    hist_kernel<<<(E + 255) / 256, 256, 0, stream>>>(ei, cursor, E);
    scan_block_sum<<<nb, 256, 0, stream>>>(cursor, bsum, N);
    scan_bsums<<<1, 64, 0, stream>>>(bsum, nb);
    scan_write<<<nb, 256, 0, stream>>>(cursor, bsum, rowptr, N, E);
    scatter_kernel<<<(E + 255) / 256, 256, 0, stream>>>(ei, eattr, cursor, ebuf, E);

    // weight pre-pack (once per call)
    pack_w1_kernel<<<(LAYERS * 16 * 4 * 64 + 255) / 256, 256, 0, stream>>>(W1, w1h, w1l);
    pack_w2_kernel<<<(LAYERS * 8 * 8 * 64 + 255) / 256, 256, 0, stream>>>(W2, w2h, w2l);

    for (int l = 0; l < LAYERS; ++l) {
        agg_gather_kernel<<<(N * 64 + 255) / 256, 256, 0, stream>>>(rowptr, ebuf, bond_e, h, agg, N);
        mlp_mfma_kernel<<<(N + 31) / 32, 256, 0, stream>>>(h, agg,
                                                           w1h + (size_t)l * 32768, w1l + (size_t)l * 32768,
                                                           w2h + (size_t)l * 32768, w2l + (size_t)l * 32768,
                                                           b1 + (size_t)l * 256, b2 + (size_t)l * 128,
                                                           agg, N);
        hipMemsetAsync(stats, 0, 256 * sizeof(float), stream);
        bn_reduce_kernel<<<2048, 256, 0, stream>>>(agg, stats, N);
        bn_apply_kernel<<<(nf4 + 255) / 256, 256, 0, stream>>>(agg, stats, gamma + (size_t)l * 128,
                                                               beta + (size_t)l * 128, h, N, invN,
                                                               (l < LAYERS - 1) ? 1 : 0);
    }

    pool_seg_kernel<<<(G + 3) / 4, 256, 0, stream>>>(h, batch, (float*)d_out, N, G);
}

// Round 5
// 1707.094 us; speedup vs baseline: 5.2691x; 1.3414x over previous
//
#include <hip/hip_runtime.h>

#define LAYERS 5
#define STATS_NB 64

typedef __attribute__((ext_vector_type(8))) short short8v;
typedef __attribute__((ext_vector_type(4))) float f32x4;

#define MFMA(a, b, c) __builtin_amdgcn_mfma_f32_16x16x32_bf16(a, b, c, 0, 0, 0)

__device__ __forceinline__ void atomAddF(float* p, float v) {
    __hip_atomic_fetch_add(p, v, __ATOMIC_RELAXED, __HIP_MEMORY_SCOPE_AGENT);
}

// ---- bf16 helpers ----
__device__ __forceinline__ float b2f(unsigned short u) { return __uint_as_float(((unsigned)u) << 16); }
__device__ __forceinline__ unsigned short f2b(float f) {
    unsigned int x = __float_as_uint(f);
    x += 0x7fff + ((x >> 16) & 1);
    return (unsigned short)(x >> 16);
}
__device__ __forceinline__ void st4(unsigned short* p, float4 v) {
    ushort4 u;
    u.x = f2b(v.x); u.y = f2b(v.y); u.z = f2b(v.z); u.w = f2b(v.w);
    *(ushort4*)p = u;
}

// h[i] = atom_emb[x[i*9]]  (bf16 store)
__global__ void init_h_kernel(const int* __restrict__ x, const float* __restrict__ atom_emb,
                              unsigned short* __restrict__ h, int N) {
    int tid = blockIdx.x * blockDim.x + threadIdx.x;
    if (tid >= N * 32) return;
    int i = tid >> 5;
    int c4 = (tid & 31) << 2;
    int a = x[i * 9];
    float4 v = *(const float4*)(atom_emb + a * 128 + c4);
    st4(h + (size_t)i * 128 + c4, v);
}

// ---------------- CSR build (once per call) ----------------
__global__ void hist_kernel(const int* __restrict__ ei, int* __restrict__ cnt, int E) {
    int e = blockIdx.x * blockDim.x + threadIdx.x;
    if (e < E) atomicAdd(&cnt[ei[E + e]], 1);
}

__global__ void scan_block_sum(const int* __restrict__ cnt, int* __restrict__ bsum, int N) {
    __shared__ int ls[256];
    int base = blockIdx.x * 1024;
    int tid = threadIdx.x;
    int s = 0;
#pragma unroll
    for (int j = 0; j < 4; ++j) {
        int i = base + tid * 4 + j;
        if (i < N) s += cnt[i];
    }
    ls[tid] = s;
    __syncthreads();
    for (int off = 128; off > 0; off >>= 1) {
        if (tid < off) ls[tid] += ls[tid + off];
        __syncthreads();
    }
    if (tid == 0) bsum[blockIdx.x] = ls[0];
}

__global__ void scan_bsums(int* __restrict__ bsum, int nb) {
    if (blockIdx.x == 0 && threadIdx.x == 0) {
        int acc = 0;
        for (int i = 0; i < nb; ++i) { int v = bsum[i]; bsum[i] = acc; acc += v; }
    }
}

__global__ void scan_write(int* __restrict__ cnt_cursor, const int* __restrict__ bsum,
                           int* __restrict__ rowptr, int N, int E) {
    __shared__ int ls[256];
    int base = blockIdx.x * 1024;
    int tid = threadIdx.x;
    int v[4];
    int s = 0;
#pragma unroll
    for (int j = 0; j < 4; ++j) {
        int i = base + tid * 4 + j;
        v[j] = (i < N) ? cnt_cursor[i] : 0;
        s += v[j];
    }
    ls[tid] = s;
    __syncthreads();
    if (tid == 0) {
        int acc = 0;
        for (int i = 0; i < 256; ++i) { int t = ls[i]; ls[i] = acc; acc += t; }
    }
    __syncthreads();
    int off = bsum[blockIdx.x] + ls[tid];
#pragma unroll
    for (int j = 0; j < 4; ++j) {
        int i = base + tid * 4 + j;
        if (i < N) {
            rowptr[i] = off;
            cnt_cursor[i] = off;
            off += v[j];
        }
    }
    if (blockIdx.x == 0 && tid == 0) rowptr[N] = E;
}

__global__ void scatter_kernel(const int* __restrict__ ei, const int* __restrict__ eattr,
                               int* __restrict__ cursor, int* __restrict__ ebuf, int E) {
    int e = blockIdx.x * blockDim.x + threadIdx.x;
    if (e >= E) return;
    int d = ei[E + e];
    int pos = atomicAdd(&cursor[d], 1);
    ebuf[pos] = ei[e] | (eattr[e * 3] << 24);
}

// ---------------- weight pre-pack (hi/lo bf16, fragment order) ----------------
__global__ void pack_w1_kernel(const float* __restrict__ W1,
                               unsigned short* __restrict__ wh, unsigned short* __restrict__ wl) {
    int tid = blockIdx.x * blockDim.x + threadIdx.x;
    if (tid >= LAYERS * 16 * 4 * 64) return;
    int lane = tid & 63;
    int ks = (tid >> 6) & 3;
    int nt = (tid >> 8) & 15;
    int l  = tid >> 12;
    int n  = nt * 16 + (lane & 15);
    int k0 = ks * 32 + ((lane >> 4) << 3);
    unsigned short hh[8], ll[8];
#pragma unroll
    for (int j = 0; j < 8; ++j) {
        float v = W1[((size_t)l * 128 + k0 + j) * 256 + n];
        hh[j] = f2b(v);
        ll[j] = f2b(v - b2f(hh[j]));
    }
    size_t off = (size_t)tid * 8;
    *(ushort4*)(wh + off)     = make_ushort4(hh[0], hh[1], hh[2], hh[3]);
    *(ushort4*)(wh + off + 4) = make_ushort4(hh[4], hh[5], hh[6], hh[7]);
    *(ushort4*)(wl + off)     = make_ushort4(ll[0], ll[1], ll[2], ll[3]);
    *(ushort4*)(wl + off + 4) = make_ushort4(ll[4], ll[5], ll[6], ll[7]);
}

__global__ void pack_w2_kernel(const float* __restrict__ W2,
                               unsigned short* __restrict__ wh, unsigned short* __restrict__ wl) {
    int tid = blockIdx.x * blockDim.x + threadIdx.x;
    if (tid >= LAYERS * 8 * 8 * 64) return;
    int lane = tid & 63;
    int ks = (tid >> 6) & 7;
    int nt = (tid >> 9) & 7;
    int l  = tid >> 12;
    int n  = nt * 16 + (lane & 15);
    int k0 = ks * 32 + ((lane >> 4) << 3);
    unsigned short hh[8], ll[8];
#pragma unroll
    for (int j = 0; j < 8; ++j) {
        float v = W2[((size_t)l * 256 + k0 + j) * 128 + n];
        hh[j] = f2b(v);
        ll[j] = f2b(v - b2f(hh[j]));
    }
    size_t off = (size_t)tid * 8;
    *(ushort4*)(wh + off)     = make_ushort4(hh[0], hh[1], hh[2], hh[3]);
    *(ushort4*)(wh + off + 4) = make_ushort4(hh[4], hh[5], hh[6], hh[7]);
    *(ushort4*)(wl + off)     = make_ushort4(ll[0], ll[1], ll[2], ll[3]);
    *(ushort4*)(wl + off + 4) = make_ushort4(ll[4], ll[5], ll[6], ll[7]);
}

// ---------------- fused per-layer kernel ----------------
// x = h[row] + sum_in-edges relu(h[src]+bond); z = relu(x@W1+b1)@W2+b2;
// partial BN stats to stats_part. 32 rows/block, 256 threads.
__global__ __launch_bounds__(256, 4) void fused_mlp_kernel(
        const unsigned short* __restrict__ h,
        const int* __restrict__ rowptr, const int* __restrict__ ebuf,
        const float* __restrict__ bond_emb,
        const unsigned short* __restrict__ w1h, const unsigned short* __restrict__ w1l,
        const unsigned short* __restrict__ w2h, const unsigned short* __restrict__ w2l,
        const float* __restrict__ b1, const float* __restrict__ b2,
        float* __restrict__ z, float* __restrict__ stats_part, int N) {
    __shared__ float bemb[8 * 128];
    __shared__ unsigned short xs_h[32][136], xs_l[32][136];
    __shared__ unsigned short ts_h[32][136], ts_l[32][136];
    int tid = threadIdx.x;
    int rowBase = blockIdx.x * 32;

    for (int i = tid; i < 1024; i += 256) bemb[i] = bond_emb[i];
    __syncthreads();

    int lane = tid & 63;
    int wv = tid >> 6;
    int c2 = lane * 2;

    // stage x = h[row] + gather, split hi/lo
    for (int rr = 0; rr < 8; ++rr) {
        int r = wv * 8 + rr;
        int row = rowBase + r;
        float x0 = 0.f, x1 = 0.f;
        if (row < N) {
            ushort2 u = *(const ushort2*)(h + (size_t)row * 128 + c2);
            x0 = b2f(u.x); x1 = b2f(u.y);
            int beg = rowptr[row], end = rowptr[row + 1];
            for (int j = beg; j < end; ++j) {
                int ee = ebuf[j];
                int s = ee & 0xFFFFFF;
                int b = ee >> 24;
                ushort2 hu = *(const ushort2*)(h + (size_t)s * 128 + c2);
                x0 += fmaxf(b2f(hu.x) + bemb[b * 128 + c2], 0.f);
                x1 += fmaxf(b2f(hu.y) + bemb[b * 128 + c2 + 1], 0.f);
            }
        }
        unsigned short h0 = f2b(x0), h1 = f2b(x1);
        unsigned short l0 = f2b(x0 - b2f(h0)), l1 = f2b(x1 - b2f(h1));
        *(unsigned int*)(&xs_h[r][c2]) = (unsigned)h0 | ((unsigned)h1 << 16);
        *(unsigned int*)(&xs_l[r][c2]) = (unsigned)l0 | ((unsigned)l1 << 16);
    }
    __syncthreads();

    int lrow = lane & 15;
    int lk8 = (lane >> 4) << 3;
    int rgrp = (lane >> 4) << 2;

    f32x4 acc2[2][2];
#pragma unroll
    for (int mt = 0; mt < 2; ++mt)
#pragma unroll
        for (int t = 0; t < 2; ++t) acc2[mt][t] = (f32x4){0.f, 0.f, 0.f, 0.f};

#pragma unroll
    for (int half = 0; half < 2; ++half) {
        // GEMM1 for this N-half: t[:, half*128 .. half*128+128)
        f32x4 acc1[2][2];
#pragma unroll
        for (int mt = 0; mt < 2; ++mt)
#pragma unroll
            for (int t = 0; t < 2; ++t) acc1[mt][t] = (f32x4){0.f, 0.f, 0.f, 0.f};

#pragma unroll
        for (int ks = 0; ks < 4; ++ks) {
            int kb = ks * 32 + lk8;
            short8v ah0 = *(const short8v*)(&xs_h[lrow][kb]);
            short8v al0 = *(const short8v*)(&xs_l[lrow][kb]);
            short8v ah1 = *(const short8v*)(&xs_h[16 + lrow][kb]);
            short8v al1 = *(const short8v*)(&xs_l[16 + lrow][kb]);
#pragma unroll
            for (int t = 0; t < 2; ++t) {
                int nt = half * 8 + wv * 2 + t;
                size_t off = ((size_t)(nt * 4 + ks) * 64 + lane) * 8;
                short8v wh = *(const short8v*)(w1h + off);
                short8v wl = *(const short8v*)(w1l + off);
                acc1[0][t] = MFMA(al0, wh, acc1[0][t]);
                acc1[0][t] = MFMA(ah0, wl, acc1[0][t]);
                acc1[0][t] = MFMA(ah0, wh, acc1[0][t]);
                acc1[1][t] = MFMA(al1, wh, acc1[1][t]);
                acc1[1][t] = MFMA(ah1, wl, acc1[1][t]);
                acc1[1][t] = MFMA(ah1, wh, acc1[1][t]);
            }
        }

        if (half) __syncthreads();   // all waves done reading ts from previous half

        // epilogue: t = relu(acc1 + b1) -> ts hi/lo (local cols 0..127)
#pragma unroll
        for (int t = 0; t < 2; ++t) {
            int coll = (wv * 2 + t) * 16 + lrow;
            float bb = b1[half * 128 + coll];
#pragma unroll
            for (int mt = 0; mt < 2; ++mt) {
                int row0 = mt * 16 + rgrp;
#pragma unroll
                for (int r = 0; r < 4; ++r) {
                    float tv = fmaxf(acc1[mt][t][r] + bb, 0.f);
                    unsigned short th = f2b(tv);
                    ts_h[row0 + r][coll] = th;
                    ts_l[row0 + r][coll] = f2b(tv - b2f(th));
                }
            }
        }
        __syncthreads();

        // GEMM2 partial: K-cols half*128..+128 of t
#pragma unroll
        for (int ksl = 0; ksl < 4; ++ksl) {
            int kb = ksl * 32 + lk8;
            short8v ah0 = *(const short8v*)(&ts_h[lrow][kb]);
            short8v al0 = *(const short8v*)(&ts_l[lrow][kb]);
            short8v ah1 = *(const short8v*)(&ts_h[16 + lrow][kb]);
            short8v al1 = *(const short8v*)(&ts_l[16 + lrow][kb]);
#pragma unroll
            for (int t = 0; t < 2; ++t) {
                int nt = wv * 2 + t;
                int ks = half * 4 + ksl;
                size_t off = ((size_t)(nt * 8 + ks) * 64 + lane) * 8;
                short8v wh = *(const short8v*)(w2h + off);
                short8v wl = *(const short8v*)(w2l + off);
                acc2[0][t] = MFMA(al0, wh, acc2[0][t]);
                acc2[0][t] = MFMA(ah0, wl, acc2[0][t]);
                acc2[0][t] = MFMA(ah0, wh, acc2[0][t]);
                acc2[1][t] = MFMA(al1, wh, acc2[1][t]);
                acc2[1][t] = MFMA(ah1, wl, acc2[1][t]);
                acc2[1][t] = MFMA(ah1, wh, acc2[1][t]);
            }
        }
    }

    // final epilogue: z = acc2 + b2, plus partial BN stats
#pragma unroll
    for (int t = 0; t < 2; ++t) {
        int col = (wv * 2 + t) * 16 + lrow;
        float bb = b2[col];
        float s = 0.f, q = 0.f;
#pragma unroll
        for (int mt = 0; mt < 2; ++mt) {
#pragma unroll
            for (int r = 0; r < 4; ++r) {
                int row = rowBase + mt * 16 + rgrp + r;
                if (row < N) {
                    float zv = acc2[mt][t][r] + bb;
                    z[(size_t)row * 128 + col] = zv;
                    s += zv;
                    q += zv * zv;
                }
            }
        }
        s += __shfl_xor(s, 16, 64);
        s += __shfl_xor(s, 32, 64);
        q += __shfl_xor(q, 16, 64);
        q += __shfl_xor(q, 32, 64);
        if (lane < 16) {
            float* sp = stats_part + (size_t)(blockIdx.x & (STATS_NB - 1)) * 256;
            atomAddF(sp + col, s);
            atomAddF(sp + 128 + col, q);
        }
    }
}

__global__ void reduce_stats_kernel(const float* __restrict__ part, float* __restrict__ stats) {
    int c = threadIdx.x;   // 256
    float s = 0.f;
    for (int i = 0; i < STATS_NB; ++i) s += part[i * 256 + c];
    stats[c] = s;
}

__global__ void bn_apply_kernel(const float* __restrict__ z, const float* __restrict__ stats,
                                const float* __restrict__ gamma, const float* __restrict__ beta,
                                unsigned short* __restrict__ h, int N, float invN, int do_relu) {
    int tid = blockIdx.x * blockDim.x + threadIdx.x;
    if (tid >= N * 32) return;
    int i = tid >> 5;
    int c4 = (tid & 31) << 2;
    float4 v = *(const float4*)(z + (size_t)i * 128 + c4);
    float vv[4] = {v.x, v.y, v.z, v.w};
    float ov[4];
#pragma unroll
    for (int j = 0; j < 4; ++j) {
        int c = c4 + j;
        float mean = stats[c] * invN;
        float var = stats[128 + c] * invN - mean * mean;
        float sc = rsqrtf(var + 1e-5f) * gamma[c];
        float o = (vv[j] - mean) * sc + beta[c];
        if (do_relu) o = fmaxf(o, 0.f);
        ov[j] = o;
    }
    st4(h + (size_t)i * 128 + c4, make_float4(ov[0], ov[1], ov[2], ov[3]));
}

// segmented pool over sorted batch: one wave per graph, no atomics.
__global__ __launch_bounds__(256) void pool_seg_kernel(const unsigned short* __restrict__ h,
                                                       const int* __restrict__ batch,
                                                       float* __restrict__ out, int N, int G) {
    int g = blockIdx.x * 4 + (threadIdx.x >> 6);
    if (g >= G) return;
    int lane = threadIdx.x & 63;
    int lo = 0, hi = N;
    while (lo < hi) { int m = (lo + hi) >> 1; if (batch[m] < g) lo = m + 1; else hi = m; }
    int s = lo;
    hi = N;
    while (lo < hi) { int m = (lo + hi) >> 1; if (batch[m] < g + 1) lo = m + 1; else hi = m; }
    int e = lo;
    int c2 = lane * 2;
    float a0 = 0.f, a1 = 0.f;
    for (int i = s; i < e; ++i) {
        ushort2 u = *(const ushort2*)(h + (size_t)i * 128 + c2);
        a0 += b2f(u.x);
        a1 += b2f(u.y);
    }
    *(float2*)(out + (size_t)g * 128 + c2) = make_float2(a0, a1);
}

extern "C" void kernel_launch(void* const* d_in, const int* in_sizes, int n_in,
                              void* d_out, int out_size, void* d_ws, size_t ws_size,
                              hipStream_t stream) {
    const int* x        = (const int*)d_in[0];
    const int* ei       = (const int*)d_in[1];
    const int* eattr    = (const int*)d_in[2];
    const int* batch    = (const int*)d_in[3];
    const float* atom_e = (const float*)d_in[4];
    const float* bond_e = (const float*)d_in[5];
    const float* W1     = (const float*)d_in[6];
    const float* b1     = (const float*)d_in[7];
    const float* W2     = (const float*)d_in[8];
    const float* b2     = (const float*)d_in[9];
    const float* gamma  = (const float*)d_in[10];
    const float* beta   = (const float*)d_in[11];

    int N = in_sizes[0] / 9;
    int E = in_sizes[1] / 2;
    int G = out_size / 128;

    auto align = [](size_t v) { return (v + 255) & ~(size_t)255; };
    char* ws = (char*)d_ws;
    unsigned short* h = (unsigned short*)ws; ws += align((size_t)N * 128 * 2);
    float* z     = (float*)ws;               ws += align((size_t)N * 128 * 4);
    int* rowptr  = (int*)ws;                 ws += align((size_t)(N + 1) * 4);
    int* cursor  = (int*)ws;                 ws += align((size_t)N * 4);
    int* ebuf    = (int*)ws;                 ws += align((size_t)E * 4);
    int* bsum    = (int*)ws;                 ws += align((size_t)4096 * 4);
    unsigned short* w1h = (unsigned short*)ws; ws += align((size_t)LAYERS * 32768 * 2);
    unsigned short* w1l = (unsigned short*)ws; ws += align((size_t)LAYERS * 32768 * 2);
    unsigned short* w2h = (unsigned short*)ws; ws += align((size_t)LAYERS * 32768 * 2);
    unsigned short* w2l = (unsigned short*)ws; ws += align((size_t)LAYERS * 32768 * 2);
    float* stats_part = (float*)ws;          ws += align((size_t)STATS_NB * 256 * 4);
    float* stats = (float*)ws;

    float invN = 1.0f / (float)N;
    int nf4 = N * 32;
    int nb = (N + 1023) / 1024;

    init_h_kernel<<<(nf4 + 255) / 256, 256, 0, stream>>>(x, atom_e, h, N);

    // CSR build (once per call)
    hipMemsetAsync(cursor, 0, (size_t)N * 4, stream);
    hist_kernel<<<(E + 255) / 256, 256, 0, stream>>>(ei, cursor, E);
    scan_block_sum<<<nb, 256, 0, stream>>>(cursor, bsum, N);
    scan_bsums<<<1, 64, 0, stream>>>(bsum, nb);
    scan_write<<<nb, 256, 0, stream>>>(cursor, bsum, rowptr, N, E);
    scatter_kernel<<<(E + 255) / 256, 256, 0, stream>>>(ei, eattr, cursor, ebuf, E);

    // weight pre-pack (once per call)
    pack_w1_kernel<<<(LAYERS * 16 * 4 * 64 + 255) / 256, 256, 0, stream>>>(W1, w1h, w1l);
    pack_w2_kernel<<<(LAYERS * 8 * 8 * 64 + 255) / 256, 256, 0, stream>>>(W2, w2h, w2l);

    for (int l = 0; l < LAYERS; ++l) {
        hipMemsetAsync(stats_part, 0, (size_t)STATS_NB * 256 * 4, stream);
        fused_mlp_kernel<<<(N + 31) / 32, 256, 0, stream>>>(
            h, rowptr, ebuf, bond_e,
            w1h + (size_t)l * 32768, w1l + (size_t)l * 32768,
            w2h + (size_t)l * 32768, w2l + (size_t)l * 32768,
            b1 + (size_t)l * 256, b2 + (size_t)l * 128,
            z, stats_part, N);
        reduce_stats_kernel<<<1, 256, 0, stream>>>(stats_part, stats);
        bn_apply_kernel<<<(nf4 + 255) / 256, 256, 0, stream>>>(z, stats, gamma + (size_t)l * 128,
                                                               beta + (size_t)l * 128, h, N, invN,
                                                               (l < LAYERS - 1) ? 1 : 0);
    }

    pool_seg_kernel<<<(G + 3) / 4, 256, 0, stream>>>(h, batch, (float*)d_out, N, G);
}

// Round 6
// 1549.614 us; speedup vs baseline: 5.8046x; 1.1016x over previous
//
#include <hip/hip_runtime.h>

#define LAYERS 5
#define STATS_NB 64

typedef __attribute__((ext_vector_type(8))) short short8v;
typedef __attribute__((ext_vector_type(4))) float f32x4;

#define MFMA(a, b, c) __builtin_amdgcn_mfma_f32_16x16x32_bf16(a, b, c, 0, 0, 0)

__device__ __forceinline__ void atomAddF(float* p, float v) {
    __hip_atomic_fetch_add(p, v, __ATOMIC_RELAXED, __HIP_MEMORY_SCOPE_AGENT);
}

// ---- bf16 helpers ----
__device__ __forceinline__ float b2f(unsigned short u) { return __uint_as_float(((unsigned)u) << 16); }
__device__ __forceinline__ unsigned short f2b(float f) {
    unsigned int x = __float_as_uint(f);
    x += 0x7fff + ((x >> 16) & 1);
    return (unsigned short)(x >> 16);
}
__device__ __forceinline__ void st4(unsigned short* p, float4 v) {
    ushort4 u;
    u.x = f2b(v.x); u.y = f2b(v.y); u.z = f2b(v.z); u.w = f2b(v.w);
    *(ushort4*)p = u;
}

// h[i] = atom_emb[x[i*9]]  (bf16 store)
__global__ void init_h_kernel(const int* __restrict__ x, const float* __restrict__ atom_emb,
                              unsigned short* __restrict__ h, int N) {
    int tid = blockIdx.x * blockDim.x + threadIdx.x;
    if (tid >= N * 32) return;
    int i = tid >> 5;
    int c4 = (tid & 31) << 2;
    int a = x[i * 9];
    float4 v = *(const float4*)(atom_emb + a * 128 + c4);
    st4(h + (size_t)i * 128 + c4, v);
}

// ---------------- CSR build (once per call) ----------------
__global__ void hist_kernel(const int* __restrict__ ei, int* __restrict__ cnt, int E) {
    int e = blockIdx.x * blockDim.x + threadIdx.x;
    if (e < E) atomicAdd(&cnt[ei[E + e]], 1);
}

__global__ void scan_block_sum(const int* __restrict__ cnt, int* __restrict__ bsum, int N) {
    __shared__ int ls[256];
    int base = blockIdx.x * 1024;
    int tid = threadIdx.x;
    int s = 0;
#pragma unroll
    for (int j = 0; j < 4; ++j) {
        int i = base + tid * 4 + j;
        if (i < N) s += cnt[i];
    }
    ls[tid] = s;
    __syncthreads();
    for (int off = 128; off > 0; off >>= 1) {
        if (tid < off) ls[tid] += ls[tid + off];
        __syncthreads();
    }
    if (tid == 0) bsum[blockIdx.x] = ls[0];
}

__global__ void scan_bsums(int* __restrict__ bsum, int nb) {
    if (blockIdx.x == 0 && threadIdx.x == 0) {
        int acc = 0;
        for (int i = 0; i < nb; ++i) { int v = bsum[i]; bsum[i] = acc; acc += v; }
    }
}

__global__ void scan_write(int* __restrict__ cnt_cursor, const int* __restrict__ bsum,
                           int* __restrict__ rowptr, int N, int E) {
    __shared__ int ls[256];
    int base = blockIdx.x * 1024;
    int tid = threadIdx.x;
    int v[4];
    int s = 0;
#pragma unroll
    for (int j = 0; j < 4; ++j) {
        int i = base + tid * 4 + j;
        v[j] = (i < N) ? cnt_cursor[i] : 0;
        s += v[j];
    }
    ls[tid] = s;
    __syncthreads();
    if (tid == 0) {
        int acc = 0;
        for (int i = 0; i < 256; ++i) { int t = ls[i]; ls[i] = acc; acc += t; }
    }
    __syncthreads();
    int off = bsum[blockIdx.x] + ls[tid];
#pragma unroll
    for (int j = 0; j < 4; ++j) {
        int i = base + tid * 4 + j;
        if (i < N) {
            rowptr[i] = off;
            cnt_cursor[i] = off;
            off += v[j];
        }
    }
    if (blockIdx.x == 0 && tid == 0) rowptr[N] = E;
}

__global__ void scatter_kernel(const int* __restrict__ ei, const int* __restrict__ eattr,
                               int* __restrict__ cursor, int* __restrict__ ebuf, int E) {
    int e = blockIdx.x * blockDim.x + threadIdx.x;
    if (e >= E) return;
    int d = ei[E + e];
    int pos = atomicAdd(&cursor[d], 1);
    ebuf[pos] = ei[e] | (eattr[e * 3] << 24);
}

// ---------------- weight pre-pack (hi/lo bf16, fragment order) ----------------
__global__ void pack_w1_kernel(const float* __restrict__ W1,
                               unsigned short* __restrict__ wh, unsigned short* __restrict__ wl) {
    int tid = blockIdx.x * blockDim.x + threadIdx.x;
    if (tid >= LAYERS * 16 * 4 * 64) return;
    int lane = tid & 63;
    int ks = (tid >> 6) & 3;
    int nt = (tid >> 8) & 15;
    int l  = tid >> 12;
    int n  = nt * 16 + (lane & 15);
    int k0 = ks * 32 + ((lane >> 4) << 3);
    unsigned short hh[8], ll[8];
#pragma unroll
    for (int j = 0; j < 8; ++j) {
        float v = W1[((size_t)l * 128 + k0 + j) * 256 + n];
        hh[j] = f2b(v);
        ll[j] = f2b(v - b2f(hh[j]));
    }
    size_t off = (size_t)tid * 8;
    *(ushort4*)(wh + off)     = make_ushort4(hh[0], hh[1], hh[2], hh[3]);
    *(ushort4*)(wh + off + 4) = make_ushort4(hh[4], hh[5], hh[6], hh[7]);
    *(ushort4*)(wl + off)     = make_ushort4(ll[0], ll[1], ll[2], ll[3]);
    *(ushort4*)(wl + off + 4) = make_ushort4(ll[4], ll[5], ll[6], ll[7]);
}

__global__ void pack_w2_kernel(const float* __restrict__ W2,
                               unsigned short* __restrict__ wh, unsigned short* __restrict__ wl) {
    int tid = blockIdx.x * blockDim.x + threadIdx.x;
    if (tid >= LAYERS * 8 * 8 * 64) return;
    int lane = tid & 63;
    int ks = (tid >> 6) & 7;
    int nt = (tid >> 9) & 7;
    int l  = tid >> 12;
    int n  = nt * 16 + (lane & 15);
    int k0 = ks * 32 + ((lane >> 4) << 3);
    unsigned short hh[8], ll[8];
#pragma unroll
    for (int j = 0; j < 8; ++j) {
        float v = W2[((size_t)l * 256 + k0 + j) * 128 + n];
        hh[j] = f2b(v);
        ll[j] = f2b(v - b2f(hh[j]));
    }
    size_t off = (size_t)tid * 8;
    *(ushort4*)(wh + off)     = make_ushort4(hh[0], hh[1], hh[2], hh[3]);
    *(ushort4*)(wh + off + 4) = make_ushort4(hh[4], hh[5], hh[6], hh[7]);
    *(ushort4*)(wl + off)     = make_ushort4(ll[0], ll[1], ll[2], ll[3]);
    *(ushort4*)(wl + off + 4) = make_ushort4(ll[4], ll[5], ll[6], ll[7]);
}

// ---------------- fused per-layer kernel ----------------
// BM=64 rows/block, 512 threads (8 waves, 2M x 4N wave grid).
// x = h[row] + sum_in-edges relu(h[src]+bond); z = relu(x@W1+b1)@W2+b2;
// partial BN stats to stats_part.
__global__ __launch_bounds__(512, 4) void fused_mlp_kernel(
        const unsigned short* __restrict__ h,
        const int* __restrict__ rowptr, const int* __restrict__ ebuf,
        const float* __restrict__ bond_emb,
        const unsigned short* __restrict__ w1h, const unsigned short* __restrict__ w1l,
        const unsigned short* __restrict__ w2h, const unsigned short* __restrict__ w2l,
        const float* __restrict__ b1, const float* __restrict__ b2,
        float* __restrict__ z, float* __restrict__ stats_part, int N) {
    __shared__ float bemb[8 * 128];
    __shared__ unsigned short xs_h[64][136], xs_l[64][136];
    __shared__ unsigned short ts_h[64][136], ts_l[64][136];
    int tid = threadIdx.x;
    int rowBase = blockIdx.x * 64;

    for (int i = tid; i < 1024; i += 512) bemb[i] = bond_emb[i];
    __syncthreads();

    int lane = tid & 63;
    int wv = tid >> 6;          // 0..7
    int hw = lane >> 5;         // half-wave 0/1
    int c4 = (lane & 31) << 2;  // 0..124

    // stage x = h[row] + gather; 2 rows in flight per wave (half-wave per row)
#pragma unroll
    for (int it = 0; it < 4; ++it) {
        int r = wv * 8 + it * 2 + hw;
        int row = rowBase + r;
        float xv[4] = {0.f, 0.f, 0.f, 0.f};
        if (row < N) {
            ushort4 u = *(const ushort4*)(h + (size_t)row * 128 + c4);
            xv[0] = b2f(u.x); xv[1] = b2f(u.y); xv[2] = b2f(u.z); xv[3] = b2f(u.w);
            int beg = rowptr[row], end = rowptr[row + 1];
            for (int j = beg; j < end; ++j) {
                int ee = ebuf[j];
                int s = ee & 0xFFFFFF;
                int b = ee >> 24;
                ushort4 hu = *(const ushort4*)(h + (size_t)s * 128 + c4);
                float4 bv = *(const float4*)(bemb + b * 128 + c4);
                xv[0] += fmaxf(b2f(hu.x) + bv.x, 0.f);
                xv[1] += fmaxf(b2f(hu.y) + bv.y, 0.f);
                xv[2] += fmaxf(b2f(hu.z) + bv.z, 0.f);
                xv[3] += fmaxf(b2f(hu.w) + bv.w, 0.f);
            }
        }
        unsigned short hh[4], ll[4];
#pragma unroll
        for (int i = 0; i < 4; ++i) {
            hh[i] = f2b(xv[i]);
            ll[i] = f2b(xv[i] - b2f(hh[i]));
        }
        *(ushort4*)(&xs_h[r][c4]) = make_ushort4(hh[0], hh[1], hh[2], hh[3]);
        *(ushort4*)(&xs_l[r][c4]) = make_ushort4(ll[0], ll[1], ll[2], ll[3]);
    }
    __syncthreads();

    int lrow = lane & 15;
    int lk8 = (lane >> 4) << 3;
    int rgrp = (lane >> 4) << 2;
    int wm = wv >> 2;   // 0..1  (M dimension)
    int wn = wv & 3;    // 0..3  (N dimension)

    f32x4 acc2[2][2];
#pragma unroll
    for (int mt = 0; mt < 2; ++mt)
#pragma unroll
        for (int t = 0; t < 2; ++t) acc2[mt][t] = (f32x4){0.f, 0.f, 0.f, 0.f};

#pragma unroll
    for (int half = 0; half < 2; ++half) {
        // GEMM1 for this N-half of t: cols half*128 .. half*128+128
        f32x4 acc1[2][2];
#pragma unroll
        for (int mt = 0; mt < 2; ++mt)
#pragma unroll
            for (int t = 0; t < 2; ++t) acc1[mt][t] = (f32x4){0.f, 0.f, 0.f, 0.f};

#pragma unroll
        for (int ks = 0; ks < 4; ++ks) {
            int kb = ks * 32 + lk8;
            short8v ah[2], al[2];
#pragma unroll
            for (int mt = 0; mt < 2; ++mt) {
                int mrow = (wm * 2 + mt) * 16 + lrow;
                ah[mt] = *(const short8v*)(&xs_h[mrow][kb]);
                al[mt] = *(const short8v*)(&xs_l[mrow][kb]);
            }
#pragma unroll
            for (int t = 0; t < 2; ++t) {
                int nt = half * 8 + wn * 2 + t;
                size_t off = ((size_t)(nt * 4 + ks) * 64 + lane) * 8;
                short8v wh = *(const short8v*)(w1h + off);
                short8v wl = *(const short8v*)(w1l + off);
#pragma unroll
                for (int mt = 0; mt < 2; ++mt) {
                    acc1[mt][t] = MFMA(al[mt], wh, acc1[mt][t]);
                    acc1[mt][t] = MFMA(ah[mt], wl, acc1[mt][t]);
                    acc1[mt][t] = MFMA(ah[mt], wh, acc1[mt][t]);
                }
            }
        }

        if (half) __syncthreads();   // GEMM2-half0 done reading ts

        // epilogue: t = relu(acc1 + b1) -> ts hi/lo (local cols 0..127)
#pragma unroll
        for (int t = 0; t < 2; ++t) {
            int coll = (wn * 2 + t) * 16 + lrow;
            float bb = b1[half * 128 + coll];
#pragma unroll
            for (int mt = 0; mt < 2; ++mt) {
                int row0 = (wm * 2 + mt) * 16 + rgrp;
#pragma unroll
                for (int r = 0; r < 4; ++r) {
                    float tv = fmaxf(acc1[mt][t][r] + bb, 0.f);
                    unsigned short th = f2b(tv);
                    ts_h[row0 + r][coll] = th;
                    ts_l[row0 + r][coll] = f2b(tv - b2f(th));
                }
            }
        }
        __syncthreads();

        // GEMM2 partial: K-slice half*128..+128 of t
#pragma unroll
        for (int ksl = 0; ksl < 4; ++ksl) {
            int kb = ksl * 32 + lk8;
            short8v ah[2], al[2];
#pragma unroll
            for (int mt = 0; mt < 2; ++mt) {
                int mrow = (wm * 2 + mt) * 16 + lrow;
                ah[mt] = *(const short8v*)(&ts_h[mrow][kb]);
                al[mt] = *(const short8v*)(&ts_l[mrow][kb]);
            }
#pragma unroll
            for (int t = 0; t < 2; ++t) {
                int nt = wn * 2 + t;
                int ks = half * 4 + ksl;
                size_t off = ((size_t)(nt * 8 + ks) * 64 + lane) * 8;
                short8v wh = *(const short8v*)(w2h + off);
                short8v wl = *(const short8v*)(w2l + off);
#pragma unroll
                for (int mt = 0; mt < 2; ++mt) {
                    acc2[mt][t] = MFMA(al[mt], wh, acc2[mt][t]);
                    acc2[mt][t] = MFMA(ah[mt], wl, acc2[mt][t]);
                    acc2[mt][t] = MFMA(ah[mt], wh, acc2[mt][t]);
                }
            }
        }
    }

    // final epilogue: z = acc2 + b2, plus partial BN stats
#pragma unroll
    for (int t = 0; t < 2; ++t) {
        int col = (wn * 2 + t) * 16 + lrow;
        float bb = b2[col];
        float s = 0.f, q = 0.f;
#pragma unroll
        for (int mt = 0; mt < 2; ++mt) {
#pragma unroll
            for (int r = 0; r < 4; ++r) {
                int row = rowBase + (wm * 2 + mt) * 16 + rgrp + r;
                if (row < N) {
                    float zv = acc2[mt][t][r] + bb;
                    z[(size_t)row * 128 + col] = zv;
                    s += zv;
                    q += zv * zv;
                }
            }
        }
        s += __shfl_xor(s, 16, 64);
        s += __shfl_xor(s, 32, 64);
        q += __shfl_xor(q, 16, 64);
        q += __shfl_xor(q, 32, 64);
        if (lane < 16) {
            float* sp = stats_part + (size_t)(blockIdx.x & (STATS_NB - 1)) * 256;
            atomAddF(sp + col, s);
            atomAddF(sp + 128 + col, q);
        }
    }
}

__global__ void reduce_stats_kernel(const float* __restrict__ part, float* __restrict__ stats) {
    int c = threadIdx.x;   // 256
    float s = 0.f;
    for (int i = 0; i < STATS_NB; ++i) s += part[i * 256 + c];
    stats[c] = s;
}

__global__ void bn_apply_kernel(const float* __restrict__ z, const float* __restrict__ stats,
                                const float* __restrict__ gamma, const float* __restrict__ beta,
                                unsigned short* __restrict__ h, int N, float invN, int do_relu) {
    int tid = blockIdx.x * blockDim.x + threadIdx.x;
    if (tid >= N * 32) return;
    int i = tid >> 5;
    int c4 = (tid & 31) << 2;
    float4 v = *(const float4*)(z + (size_t)i * 128 + c4);
    float vv[4] = {v.x, v.y, v.z, v.w};
    float ov[4];
#pragma unroll
    for (int j = 0; j < 4; ++j) {
        int c = c4 + j;
        float mean = stats[c] * invN;
        float var = stats[128 + c] * invN - mean * mean;
        float sc = rsqrtf(var + 1e-5f) * gamma[c];
        float o = (vv[j] - mean) * sc + beta[c];
        if (do_relu) o = fmaxf(o, 0.f);
        ov[j] = o;
    }
    st4(h + (size_t)i * 128 + c4, make_float4(ov[0], ov[1], ov[2], ov[3]));
}

// segmented pool over sorted batch: one wave per graph, no atomics.
__global__ __launch_bounds__(256) void pool_seg_kernel(const unsigned short* __restrict__ h,
                                                       const int* __restrict__ batch,
                                                       float* __restrict__ out, int N, int G) {
    int g = blockIdx.x * 4 + (threadIdx.x >> 6);
    if (g >= G) return;
    int lane = threadIdx.x & 63;
    int lo = 0, hi = N;
    while (lo < hi) { int m = (lo + hi) >> 1; if (batch[m] < g) lo = m + 1; else hi = m; }
    int s = lo;
    hi = N;
    while (lo < hi) { int m = (lo + hi) >> 1; if (batch[m] < g + 1) lo = m + 1; else hi = m; }
    int e = lo;
    int c2 = lane * 2;
    float a0 = 0.f, a1 = 0.f;
    for (int i = s; i < e; ++i) {
        ushort2 u = *(const ushort2*)(h + (size_t)i * 128 + c2);
        a0 += b2f(u.x);
        a1 += b2f(u.y);
    }
    *(float2*)(out + (size_t)g * 128 + c2) = make_float2(a0, a1);
}

extern "C" void kernel_launch(void* const* d_in, const int* in_sizes, int n_in,
                              void* d_out, int out_size, void* d_ws, size_t ws_size,
                              hipStream_t stream) {
    const int* x        = (const int*)d_in[0];
    const int* ei       = (const int*)d_in[1];
    const int* eattr    = (const int*)d_in[2];
    const int* batch    = (const int*)d_in[3];
    const float* atom_e = (const float*)d_in[4];
    const float* bond_e = (const float*)d_in[5];
    const float* W1     = (const float*)d_in[6];
    const float* b1     = (const float*)d_in[7];
    const float* W2     = (const float*)d_in[8];
    const float* b2     = (const float*)d_in[9];
    const float* gamma  = (const float*)d_in[10];
    const float* beta   = (const float*)d_in[11];

    int N = in_sizes[0] / 9;
    int E = in_sizes[1] / 2;
    int G = out_size / 128;

    auto align = [](size_t v) { return (v + 255) & ~(size_t)255; };
    char* ws = (char*)d_ws;
    unsigned short* h = (unsigned short*)ws; ws += align((size_t)N * 128 * 2);
    float* z     = (float*)ws;               ws += align((size_t)N * 128 * 4);
    int* rowptr  = (int*)ws;                 ws += align((size_t)(N + 1) * 4);
    int* cursor  = (int*)ws;                 ws += align((size_t)N * 4);
    int* ebuf    = (int*)ws;                 ws += align((size_t)E * 4);
    int* bsum    = (int*)ws;                 ws += align((size_t)4096 * 4);
    unsigned short* w1h = (unsigned short*)ws; ws += align((size_t)LAYERS * 32768 * 2);
    unsigned short* w1l = (unsigned short*)ws; ws += align((size_t)LAYERS * 32768 * 2);
    unsigned short* w2h = (unsigned short*)ws; ws += align((size_t)LAYERS * 32768 * 2);
    unsigned short* w2l = (unsigned short*)ws; ws += align((size_t)LAYERS * 32768 * 2);
    float* stats_part = (float*)ws;          ws += align((size_t)STATS_NB * 256 * 4);
    float* stats = (float*)ws;

    float invN = 1.0f / (float)N;
    int nf4 = N * 32;
    int nb = (N + 1023) / 1024;

    init_h_kernel<<<(nf4 + 255) / 256, 256, 0, stream>>>(x, atom_e, h, N);

    // CSR build (once per call)
    hipMemsetAsync(cursor, 0, (size_t)N * 4, stream);
    hist_kernel<<<(E + 255) / 256, 256, 0, stream>>>(ei, cursor, E);
    scan_block_sum<<<nb, 256, 0, stream>>>(cursor, bsum, N);
    scan_bsums<<<1, 64, 0, stream>>>(bsum, nb);
    scan_write<<<nb, 256, 0, stream>>>(cursor, bsum, rowptr, N, E);
    scatter_kernel<<<(E + 255) / 256, 256, 0, stream>>>(ei, eattr, cursor, ebuf, E);

    // weight pre-pack (once per call)
    pack_w1_kernel<<<(LAYERS * 16 * 4 * 64 + 255) / 256, 256, 0, stream>>>(W1, w1h, w1l);
    pack_w2_kernel<<<(LAYERS * 8 * 8 * 64 + 255) / 256, 256, 0, stream>>>(W2, w2h, w2l);

    for (int l = 0; l < LAYERS; ++l) {
        hipMemsetAsync(stats_part, 0, (size_t)STATS_NB * 256 * 4, stream);
        fused_mlp_kernel<<<(N + 63) / 64, 512, 0, stream>>>(
            h, rowptr, ebuf, bond_e,
            w1h + (size_t)l * 32768, w1l + (size_t)l * 32768,
            w2h + (size_t)l * 32768, w2l + (size_t)l * 32768,
            b1 + (size_t)l * 256, b2 + (size_t)l * 128,
            z, stats_part, N);
        reduce_stats_kernel<<<1, 256, 0, stream>>>(stats_part, stats);
        bn_apply_kernel<<<(nf4 + 255) / 256, 256, 0, stream>>>(z, stats, gamma + (size_t)l * 128,
                                                               beta + (size_t)l * 128, h, N, invN,
                                                               (l < LAYERS - 1) ? 1 : 0);
    }

    pool_seg_kernel<<<(G + 3) / 4, 256, 0, stream>>>(h, batch, (float*)d_out, N, G);
}